// Round 5
// baseline (566.946 us; speedup 1.0000x reference)
//
#include <hip/hip_runtime.h>
#include <hip/hip_bf16.h>

#define N_NODES 100000
#define N_EDGES 1000000
#define DIM 64

static const long long ND = (long long)N_NODES * DIM;  // 6,400,000

typedef float f4_t __attribute__((ext_vector_type(4)));

// d_out layout (floats):
// h1: [0, ND)  h2: [ND, 2*ND)  c1c2: [2*ND, 2*ND+128)  h3: [2*ND+128, ...)  h4: [3*ND+128, ...)

// d_ws layout (4-byte words, all region bases %4 == 0 for int4/uint4 access):
#define WS_CUR1  0
#define WS_CUR2  100000
#define WS_OFF1  200000            // 100001 used, padded to 100004
#define WS_OFF2  300004
#define WS_SORT1 400008
#define WS_SORT2 1400008
#define WS_CSUM  2400008           // 128 floats
#define WS_BSUM  2400136           // 196 ints (2 graphs x 98 blocks)
#define WS_T1    2400512           // bf16 [G|S] rows, 64 words/row, 6.4M words
#define WS_T2    (WS_T1 + 6400000)
#define WS_END   (WS_T2 + 6400000) // 15,200,512 words = ~58 MB

#define SCAN_BLOCKS 98             // 98 * 1024 >= 100000

__device__ __forceinline__ unsigned pk_bf16(float a, float b) {
    __hip_bfloat16 ha = __float2bfloat16(a), hb = __float2bfloat16(b);
    return (unsigned)(*(unsigned short*)&ha) | ((unsigned)(*(unsigned short*)&hb) << 16);
}
__device__ __forceinline__ float bf_lo(unsigned u) { return __uint_as_float(u << 16); }
__device__ __forceinline__ float bf_hi(unsigned u) { return __uint_as_float(u & 0xFFFF0000u); }

__global__ __launch_bounds__(256) void k_init(int* __restrict__ ws) {
    int i = blockIdx.x * blockDim.x + threadIdx.x;
    if (i < 200000) ws[i] = 0;                                   // cursors (= histograms)
    else if (i < 200128) ((float*)ws)[WS_CSUM + (i - 200000)] = 0.f;
    else if (i == 200128) {
        ws[WS_OFF1 + N_NODES] = N_EDGES;
        ws[WS_OFF2 + N_NODES] = N_EDGES;
    }
}

__global__ __launch_bounds__(256) void k_hist(const int4* __restrict__ dst1,
                                              const int4* __restrict__ dst2,
                                              int* __restrict__ ws) {
    int i = blockIdx.x * blockDim.x + threadIdx.x;
    const int Q = N_EDGES / 4;
    if (i < Q) {
        int4 d = dst1[i];
        atomicAdd(&ws[WS_CUR1 + d.x], 1);
        atomicAdd(&ws[WS_CUR1 + d.y], 1);
        atomicAdd(&ws[WS_CUR1 + d.z], 1);
        atomicAdd(&ws[WS_CUR1 + d.w], 1);
    } else if (i < 2 * Q) {
        int4 d = dst2[i - Q];
        atomicAdd(&ws[WS_CUR2 + d.x], 1);
        atomicAdd(&ws[WS_CUR2 + d.y], 1);
        atomicAdd(&ws[WS_CUR2 + d.z], 1);
        atomicAdd(&ws[WS_CUR2 + d.w], 1);
    }
}

// Phase 1: per-block sums of 1024 counts -> bsum[g*98+b]
__global__ __launch_bounds__(256) void k_scan1(int* __restrict__ ws) {
    const int g = blockIdx.y;
    const int* hist = ws + (g ? WS_CUR2 : WS_CUR1);
    const int t = threadIdx.x;
    const int base = blockIdx.x * 1024 + t * 4;
    int4 c = make_int4(0, 0, 0, 0);
    if (base < N_NODES) c = *(const int4*)(hist + base);
    __shared__ int s[256];
    s[t] = c.x + c.y + c.z + c.w;
    __syncthreads();
    for (int d = 128; d > 0; d >>= 1) {
        if (t < d) s[t] += s[t + d];
        __syncthreads();
    }
    if (t == 0) ws[WS_BSUM + g * SCAN_BLOCKS + blockIdx.x] = s[0];
}

// Phase 2: one block scans the 196 block sums (two independent 98-segments), exclusive.
__global__ __launch_bounds__(256) void k_scan2(int* __restrict__ ws) {
    const int t = threadIdx.x;
    const int n = 2 * SCAN_BLOCKS;
    __shared__ int s[256];
    s[t] = (t < n) ? ws[WS_BSUM + t] : 0;
    __syncthreads();
    for (int d = 1; d < 256; d <<= 1) {
        int v = 0;
        if (t >= d && (t < SCAN_BLOCKS || t - d >= SCAN_BLOCKS)) v = s[t - d];
        __syncthreads();
        s[t] += v;
        __syncthreads();
    }
    if (t < n) {
        int excl = (t == 0 || t == SCAN_BLOCKS) ? 0 : s[t - 1];
        ws[WS_BSUM + t] = excl;
    }
}

// Phase 3: local exclusive scan + block offset -> off[] and cursor[]
__global__ __launch_bounds__(256) void k_scan3(int* __restrict__ ws) {
    const int g = blockIdx.y;
    int* cur = ws + (g ? WS_CUR2 : WS_CUR1);
    int* off = ws + (g ? WS_OFF2 : WS_OFF1);
    const int t = threadIdx.x;
    const int base = blockIdx.x * 1024 + t * 4;
    int4 c = make_int4(0, 0, 0, 0);
    if (base < N_NODES) c = *(const int4*)(cur + base);
    __shared__ int s[256];
    s[t] = c.x + c.y + c.z + c.w;
    __syncthreads();
    for (int d = 1; d < 256; d <<= 1) {
        int v = 0;
        if (t >= d) v = s[t - d];
        __syncthreads();
        s[t] += v;
        __syncthreads();
    }
    int excl = (t == 0) ? 0 : s[t - 1];
    int boff = ws[WS_BSUM + g * SCAN_BLOCKS + blockIdx.x];
    if (base < N_NODES) {
        int o0 = boff + excl;
        int o1 = o0 + c.x, o2 = o1 + c.y, o3 = o2 + c.z;
        int4 o = make_int4(o0, o1, o2, o3);
        *(int4*)(off + base) = o;
        *(int4*)(cur + base) = o;
    }
}

__global__ __launch_bounds__(256) void k_fill(const int4* __restrict__ src1,
                                              const int4* __restrict__ dst1,
                                              const int4* __restrict__ src2,
                                              const int4* __restrict__ dst2,
                                              int* __restrict__ ws) {
    int i = blockIdx.x * blockDim.x + threadIdx.x;
    const int Q = N_EDGES / 4;
    if (i < Q) {
        int4 sv = src1[i]; int4 dv = dst1[i];
        int p0 = atomicAdd(&ws[WS_CUR1 + dv.x], 1); ws[WS_SORT1 + p0] = sv.x;
        int p1 = atomicAdd(&ws[WS_CUR1 + dv.y], 1); ws[WS_SORT1 + p1] = sv.y;
        int p2 = atomicAdd(&ws[WS_CUR1 + dv.z], 1); ws[WS_SORT1 + p2] = sv.z;
        int p3 = atomicAdd(&ws[WS_CUR1 + dv.w], 1); ws[WS_SORT1 + p3] = sv.w;
    } else if (i < 2 * Q) {
        int e = i - Q;
        int4 sv = src2[e]; int4 dv = dst2[e];
        int p0 = atomicAdd(&ws[WS_CUR2 + dv.x], 1); ws[WS_SORT2 + p0] = sv.x;
        int p1 = atomicAdd(&ws[WS_CUR2 + dv.y], 1); ws[WS_SORT2 + p1] = sv.y;
        int p2 = atomicAdd(&ws[WS_CUR2 + dv.z], 1); ws[WS_SORT2 + p2] = sv.z;
        int p3 = atomicAdd(&ws[WS_CUR2 + dv.w], 1); ws[WS_SORT2 + p3] = sv.w;
    }
}

// Fused pre-transform, ONE launch: per node n compute
//   T1[n] = [bf16(feat@W1) | bf16(shuf@W1)], T2[n] = [bf16(feat@W2) | bf16(shuf@W2)]
// Both W1,W2 staged in LDS (32KB); each W read serves feat AND shuf accumulators.
// feat/shuf read once, nontemporal (streamed). No bias (added after aggregation).
__global__ __launch_bounds__(256) void k_transform(int* __restrict__ ws,
                                                   const float* __restrict__ feat,
                                                   const float* __restrict__ shuf,
                                                   const float* __restrict__ W1,
                                                   const float* __restrict__ W2) {
    __shared__ float Wl[2][64 * 64];
    const int t = threadIdx.x;
    for (int i = t; i < 64 * 64; i += 256) {
        Wl[0][i] = W1[i];
        Wl[1][i] = W2[i];
    }
    __syncthreads();

    const int n = blockIdx.x * 256 + t;
    if (n >= N_NODES) return;

    float af[64], as_[64];
    {
        const f4_t* f4 = (const f4_t*)(feat + (long long)n * DIM);
        const f4_t* s4 = (const f4_t*)(shuf + (long long)n * DIM);
        #pragma unroll
        for (int i = 0; i < 16; ++i) {
            f4_t v = __builtin_nontemporal_load(f4 + i);
            af[4 * i + 0] = v.x; af[4 * i + 1] = v.y;
            af[4 * i + 2] = v.z; af[4 * i + 3] = v.w;
            f4_t u = __builtin_nontemporal_load(s4 + i);
            as_[4 * i + 0] = u.x; as_[4 * i + 1] = u.y;
            as_[4 * i + 2] = u.z; as_[4 * i + 3] = u.w;
        }
    }

    uint4* T1row = (uint4*)(ws + WS_T1) + (long long)n * 16;
    uint4* T2row = (uint4*)(ws + WS_T2) + (long long)n * 16;
    const float4* W14 = (const float4*)Wl[0];
    const float4* W24 = (const float4*)Wl[1];

    #pragma unroll
    for (int jb = 0; jb < 8; ++jb) {
        float f1[8] = {0,0,0,0,0,0,0,0}, f2[8] = {0,0,0,0,0,0,0,0};
        float s1[8] = {0,0,0,0,0,0,0,0}, s2[8] = {0,0,0,0,0,0,0,0};
        #pragma unroll
        for (int k = 0; k < 64; ++k) {
            const float4 wa = W14[k * 16 + jb * 2];
            const float4 wb = W14[k * 16 + jb * 2 + 1];
            const float4 va = W24[k * 16 + jb * 2];
            const float4 vb = W24[k * 16 + jb * 2 + 1];
            const float akf = af[k], aks = as_[k];
            f1[0] += akf * wa.x; f1[1] += akf * wa.y; f1[2] += akf * wa.z; f1[3] += akf * wa.w;
            f1[4] += akf * wb.x; f1[5] += akf * wb.y; f1[6] += akf * wb.z; f1[7] += akf * wb.w;
            s1[0] += aks * wa.x; s1[1] += aks * wa.y; s1[2] += aks * wa.z; s1[3] += aks * wa.w;
            s1[4] += aks * wb.x; s1[5] += aks * wb.y; s1[6] += aks * wb.z; s1[7] += aks * wb.w;
            f2[0] += akf * va.x; f2[1] += akf * va.y; f2[2] += akf * va.z; f2[3] += akf * va.w;
            f2[4] += akf * vb.x; f2[5] += akf * vb.y; f2[6] += akf * vb.z; f2[7] += akf * vb.w;
            s2[0] += aks * va.x; s2[1] += aks * va.y; s2[2] += aks * va.z; s2[3] += aks * va.w;
            s2[4] += aks * vb.x; s2[5] += aks * vb.y; s2[6] += aks * vb.z; s2[7] += aks * vb.w;
        }
        uint4 p;
        p.x = pk_bf16(f1[0], f1[1]); p.y = pk_bf16(f1[2], f1[3]);
        p.z = pk_bf16(f1[4], f1[5]); p.w = pk_bf16(f1[6], f1[7]);
        T1row[jb] = p;                                   // T1 G-half
        p.x = pk_bf16(s1[0], s1[1]); p.y = pk_bf16(s1[2], s1[3]);
        p.z = pk_bf16(s1[4], s1[5]); p.w = pk_bf16(s1[6], s1[7]);
        T1row[8 + jb] = p;                               // T1 S-half
        p.x = pk_bf16(f2[0], f2[1]); p.y = pk_bf16(f2[2], f2[3]);
        p.z = pk_bf16(f2[4], f2[5]); p.w = pk_bf16(f2[6], f2[7]);
        T2row[jb] = p;                                   // T2 G-half
        p.x = pk_bf16(s2[0], s2[1]); p.y = pk_bf16(s2[2], s2[3]);
        p.z = pk_bf16(s2[4], s2[5]); p.w = pk_bf16(s2[6], s2[7]);
        T2row[8 + jb] = p;                               // T2 S-half
    }
}

// Gather-aggregate pre-transformed rows. blockIdx.y = graph.
// 4 waves/block, 8 nodes/wave serial. 4 edge-slots x 16 lanes x uint4.
// 2-deep unroll -> 8 independent row-loads in flight per wave.
// h stores are nontemporal so the 101MB output stream doesn't evict T from L3.
__global__ __launch_bounds__(256) void k_gather_pre(int* __restrict__ ws,
                                                    const float* __restrict__ b1,
                                                    const float* __restrict__ b2,
                                                    float* __restrict__ out) {
    const int g = blockIdx.y;
    const int* off    = ws + (g ? WS_OFF2 : WS_OFF1);
    const int* sorted = ws + (g ? WS_SORT2 : WS_SORT1);
    const uint4* T = (const uint4*)(ws + (g ? WS_T2 : WS_T1));   // 16 uint4 per row
    const float* bias = g ? b2 : b1;
    float* h_f = out + (g ? ND : 0);
    float* h_s = out + (g ? 3 * ND + 128 : 2 * ND + 128);
    float* csum = (float*)ws + WS_CSUM + g * 64;

    const int t = threadIdx.x;
    const int wave = t >> 6;
    const int lane = t & 63;
    const int slot = lane >> 4;
    const int sub = lane & 15;

    float bias8[8];
    #pragma unroll
    for (int i = 0; i < 8; ++i) bias8[i] = bias[(sub & 7) * 8 + i];

    __shared__ float red[4][8][8];
    float csum_acc[8] = {0.f, 0.f, 0.f, 0.f, 0.f, 0.f, 0.f, 0.f};

    const int nb = blockIdx.x * 32 + wave * 8;
    for (int r = 0; r < 8; ++r) {
        const int n = nb + r;
        if (n >= N_NODES) break;
        const int e0 = off[n];
        const int e1 = off[n + 1];

        float acc[8] = {0.f, 0.f, 0.f, 0.f, 0.f, 0.f, 0.f, 0.f};
        int e = e0 + slot;
        for (; e + 4 < e1; e += 8) {
            const int sA = sorted[e];
            const int sB = sorted[e + 4];
            const uint4 vA = T[sA * 16 + sub];
            const uint4 vB = T[sB * 16 + sub];
            acc[0] += bf_lo(vA.x); acc[1] += bf_hi(vA.x);
            acc[2] += bf_lo(vA.y); acc[3] += bf_hi(vA.y);
            acc[4] += bf_lo(vA.z); acc[5] += bf_hi(vA.z);
            acc[6] += bf_lo(vA.w); acc[7] += bf_hi(vA.w);
            acc[0] += bf_lo(vB.x); acc[1] += bf_hi(vB.x);
            acc[2] += bf_lo(vB.y); acc[3] += bf_hi(vB.y);
            acc[4] += bf_lo(vB.z); acc[5] += bf_hi(vB.z);
            acc[6] += bf_lo(vB.w); acc[7] += bf_hi(vB.w);
        }
        if (e < e1) {
            const int s = sorted[e];
            const uint4 v = T[s * 16 + sub];
            acc[0] += bf_lo(v.x); acc[1] += bf_hi(v.x);
            acc[2] += bf_lo(v.y); acc[3] += bf_hi(v.y);
            acc[4] += bf_lo(v.z); acc[5] += bf_hi(v.z);
            acc[6] += bf_lo(v.w); acc[7] += bf_hi(v.w);
        }
        #pragma unroll
        for (int i = 0; i < 8; ++i) {
            acc[i] += __shfl_xor(acc[i], 16);
            acc[i] += __shfl_xor(acc[i], 32);
            acc[i] += bias8[i];
        }
        if (slot == 0 && sub < 8) {
            float* p = h_f + (long long)n * DIM + sub * 8;
            f4_t v0 = {acc[0], acc[1], acc[2], acc[3]};
            f4_t v1 = {acc[4], acc[5], acc[6], acc[7]};
            __builtin_nontemporal_store(v0, (f4_t*)p);
            __builtin_nontemporal_store(v1, (f4_t*)(p + 4));
            #pragma unroll
            for (int i = 0; i < 8; ++i) csum_acc[i] += acc[i];
        } else if (slot == 1 && sub >= 8) {
            float* p = h_s + (long long)n * DIM + (sub - 8) * 8;
            f4_t v0 = {acc[0], acc[1], acc[2], acc[3]};
            f4_t v1 = {acc[4], acc[5], acc[6], acc[7]};
            __builtin_nontemporal_store(v0, (f4_t*)p);
            __builtin_nontemporal_store(v1, (f4_t*)(p + 4));
        }
    }

    if (slot == 0 && sub < 8) {
        #pragma unroll
        for (int i = 0; i < 8; ++i) red[wave][sub][i] = csum_acc[i];
    }
    __syncthreads();
    if (t < 64) {
        int su = t >> 3, i = t & 7;
        float s4 = red[0][su][i] + red[1][su][i] + red[2][su][i] + red[3][su][i];
        unsafeAtomicAdd(&csum[su * 8 + i], s4);
    }
}

// Legacy fallback (small ws): f32 gather + in-kernel shfl matmul.
__global__ __launch_bounds__(256) void k_gather_legacy(int* __restrict__ ws,
                                                       const float* __restrict__ feat,
                                                       const float* __restrict__ shuf,
                                                       const float* __restrict__ W1,
                                                       const float* __restrict__ b1,
                                                       const float* __restrict__ W2,
                                                       const float* __restrict__ b2,
                                                       float* __restrict__ out) {
    const int g = blockIdx.y;
    const int* off    = ws + (g ? WS_OFF2 : WS_OFF1);
    const int* sorted = ws + (g ? WS_SORT2 : WS_SORT1);
    const float* W    = g ? W2 : W1;
    const float* bias = g ? b2 : b1;
    float* h_f = out + (g ? ND : 0);
    float* h_s = out + (g ? 3 * ND + 128 : 2 * ND + 128);
    float* csum = (float*)ws + WS_CSUM + g * 64;

    __shared__ float Wl[64 * 64];
    __shared__ float red[4][64];
    const int t = threadIdx.x;
    for (int i = t; i < 64 * 64; i += 256) Wl[i] = W[i];
    __syncthreads();

    const int wave = t >> 6;
    const int lane = t & 63;
    const int slot = lane >> 4;
    const int sub = lane & 15;
    const float4* feat4 = (const float4*)feat;
    const float4* shuf4 = (const float4*)shuf;
    const float bj = bias[lane];
    float csum_acc = 0.f;
    const int nb = blockIdx.x * 32 + wave * 8;

    for (int r = 0; r < 8; ++r) {
        const int n = nb + r;
        if (n >= N_NODES) break;
        const int e0 = off[n], e1 = off[n + 1];
        float af0 = 0.f, af1 = 0.f, af2 = 0.f, af3 = 0.f;
        float as0 = 0.f, as1 = 0.f, as2 = 0.f, as3 = 0.f;
        for (int e = e0 + slot; e < e1; e += 4) {
            const int s = sorted[e];
            const float4 f = feat4[s * 16 + sub];
            const float4 h = shuf4[s * 16 + sub];
            af0 += f.x; af1 += f.y; af2 += f.z; af3 += f.w;
            as0 += h.x; as1 += h.y; as2 += h.z; as3 += h.w;
        }
        af0 += __shfl_xor(af0, 16); af0 += __shfl_xor(af0, 32);
        af1 += __shfl_xor(af1, 16); af1 += __shfl_xor(af1, 32);
        af2 += __shfl_xor(af2, 16); af2 += __shfl_xor(af2, 32);
        af3 += __shfl_xor(af3, 16); af3 += __shfl_xor(af3, 32);
        as0 += __shfl_xor(as0, 16); as0 += __shfl_xor(as0, 32);
        as1 += __shfl_xor(as1, 16); as1 += __shfl_xor(as1, 32);
        as2 += __shfl_xor(as2, 16); as2 += __shfl_xor(as2, 32);
        as3 += __shfl_xor(as3, 16); as3 += __shfl_xor(as3, 32);
        float hf = bj, hs = bj;
        #pragma unroll
        for (int k = 0; k < 16; ++k) {
            const float f0 = __shfl(af0, k), f1 = __shfl(af1, k),
                        f2 = __shfl(af2, k), f3 = __shfl(af3, k);
            const float s0 = __shfl(as0, k), s1 = __shfl(as1, k),
                        s2 = __shfl(as2, k), s3 = __shfl(as3, k);
            const float w0 = Wl[(4 * k + 0) * 64 + lane];
            const float w1 = Wl[(4 * k + 1) * 64 + lane];
            const float w2 = Wl[(4 * k + 2) * 64 + lane];
            const float w3 = Wl[(4 * k + 3) * 64 + lane];
            hf += f0 * w0 + f1 * w1 + f2 * w2 + f3 * w3;
            hs += s0 * w0 + s1 * w1 + s2 * w2 + s3 * w3;
        }
        h_f[(long long)n * DIM + lane] = hf;
        h_s[(long long)n * DIM + lane] = hs;
        csum_acc += hf;
    }
    red[wave][lane] = csum_acc;
    __syncthreads();
    if (wave == 0) {
        float s4 = red[0][lane] + red[1][lane] + red[2][lane] + red[3][lane];
        unsafeAtomicAdd(&csum[lane], s4);
    }
}

__global__ void k_final(const float* __restrict__ ws_csum, float* __restrict__ out_c) {
    int t = threadIdx.x;  // 0..63 -> c1, 64..127 -> c2
    float m = ws_csum[t] * (1.0f / (float)N_NODES);
    out_c[t] = 1.f / (1.f + expf(-m));
}

extern "C" void kernel_launch(void* const* d_in, const int* in_sizes, int n_in,
                              void* d_out, int out_size, void* d_ws, size_t ws_size,
                              hipStream_t stream) {
    const float* feat = (const float*)d_in[0];
    const float* shuf = (const float*)d_in[1];
    const int* src1 = (const int*)d_in[2];
    const int* dst1 = (const int*)d_in[3];
    const int* src2 = (const int*)d_in[4];
    const int* dst2 = (const int*)d_in[5];
    const float* W1 = (const float*)d_in[6];
    const float* b1 = (const float*)d_in[7];
    const float* W2 = (const float*)d_in[8];
    const float* b2 = (const float*)d_in[9];

    float* out = (float*)d_out;
    int* ws = (int*)d_ws;
    float* c_out = out + 2 * ND;

    const bool use_pre = ws_size >= (size_t)WS_END * 4;

    k_init<<<(200129 + 255) / 256, 256, 0, stream>>>(ws);
    k_hist<<<(2 * (N_EDGES / 4) + 255) / 256, 256, 0, stream>>>(
        (const int4*)dst1, (const int4*)dst2, ws);
    k_scan1<<<dim3(SCAN_BLOCKS, 2), 256, 0, stream>>>(ws);
    k_scan2<<<1, 256, 0, stream>>>(ws);
    k_scan3<<<dim3(SCAN_BLOCKS, 2), 256, 0, stream>>>(ws);
    k_fill<<<(2 * (N_EDGES / 4) + 255) / 256, 256, 0, stream>>>(
        (const int4*)src1, (const int4*)dst1, (const int4*)src2, (const int4*)dst2, ws);

    if (use_pre) {
        k_transform<<<(N_NODES + 255) / 256, 256, 0, stream>>>(ws, feat, shuf, W1, W2);
        k_gather_pre<<<dim3((N_NODES + 31) / 32, 2), 256, 0, stream>>>(ws, b1, b2, out);
    } else {
        k_gather_legacy<<<dim3((N_NODES + 31) / 32, 2), 256, 0, stream>>>(
            ws, feat, shuf, W1, b1, W2, b2, out);
    }

    k_final<<<1, 128, 0, stream>>>((const float*)ws + WS_CSUM, c_out);
}